// Round 10
// baseline (832.937 us; speedup 1.0000x reference)
//
#include <hip/hip_runtime.h>
#include <math.h>

#define NN 50000
#define NE 800000
#define INC 32
#define HIDC 64
#define OUTC 8
#define NB_SCAN ((NN + 1023) / 1024)   // 49
#define NT_TILES ((NN + 63) / 64)      // 782
#define NPAD (NT_TILES * 64)           // 50048 padded rows
#define NXCD 8
#define PCH 32                          // edge chunks per partition
#define PSZ ((NN + NXCD - 1) / NXCD)    // 6250 dsts per partition
#define ECH (NE / PCH)                  // 25000 edges per chunk (4-aligned)

__device__ __forceinline__ float gelu_exact(float x){
    return 0.5f * x * (1.0f + erff(x * 0.70710678118654752f));
}

// actual XCD id of the CU this wave runs on (HW-verified on gfx950)
__device__ __forceinline__ int xcc_id(){
    int x;
    asm volatile("s_getreg_b32 %0, hwreg(HW_REG_XCC_ID)" : "=s"(x));
    return x & (NXCD-1);
}

// accumulate out[j] += In[lane][kc*16+kk] * W[kc*16+kk][fbase+j], W stride HIDC
// fbase MUST be SGPR-uniform (readfirstlane'd) so W reads become s_load.
template<int NCH>
__device__ __forceinline__ void gemm_acc8(const float* __restrict__ inrow,
                                          const float* __restrict__ W,
                                          int fbase, float out[8]){
    #pragma unroll
    for (int kc = 0; kc < NCH; kc++){
        float4 q0 = *(const float4*)(inrow + kc*16 + 0);
        float4 q1 = *(const float4*)(inrow + kc*16 + 4);
        float4 q2 = *(const float4*)(inrow + kc*16 + 8);
        float4 q3 = *(const float4*)(inrow + kc*16 + 12);
        float in16[16] = {q0.x,q0.y,q0.z,q0.w, q1.x,q1.y,q1.z,q1.w,
                          q2.x,q2.y,q2.z,q2.w, q3.x,q3.y,q3.z,q3.w};
        #pragma unroll
        for (int kk = 0; kk < 16; kk++){
            const float* wr = W + (size_t)(kc*16+kk)*HIDC + fbase;
            #pragma unroll
            for (int j = 0; j < 8; j++)
                out[j] = fmaf(in16[kk], wr[j], out[j]);
        }
    }
}

// ---- CSR build: XCC-affine work claiming. A block reads its REAL XCD id
// and claims chunks of that XCD's dst-partition (atomic counters), then
// steals leftovers so correctness never depends on placement. All writes
// to a partition's deg/fill_pos/col lines come from one L2. ----

__device__ __forceinline__ void hist_chunk(int p, int c, int tid,
                                           const int* __restrict__ dst,
                                           int* __restrict__ deg){
    int lo = p*PSZ, hi = lo + PSZ;
    int e0 = c*ECH;
    for (int i = e0 + tid*4; i < e0 + ECH; i += 1024){
        int4 d4 = *(const int4*)(dst + i);
        if (d4.x >= lo && d4.x < hi) atomicAdd(&deg[d4.x], 1);
        if (d4.y >= lo && d4.y < hi) atomicAdd(&deg[d4.y], 1);
        if (d4.z >= lo && d4.z < hi) atomicAdd(&deg[d4.z], 1);
        if (d4.w >= lo && d4.w < hi) atomicAdd(&deg[d4.w], 1);
    }
}

__global__ __launch_bounds__(256) void k_hist_steal(const int* __restrict__ dst,
                                                    int* __restrict__ deg,
                                                    int* __restrict__ cnt){
    __shared__ int sc;
    int tid = threadIdx.x;
    int p = xcc_id();
    for(;;){
        if (tid == 0) sc = atomicAdd(&cnt[p], 1);
        __syncthreads();
        int c = sc;
        __syncthreads();
        if (c >= PCH) break;
        hist_chunk(p, c, tid, dst, deg);
    }
    for (int q = 0; q < NXCD; q++){
        for(;;){
            if (tid == 0) sc = atomicAdd(&cnt[q], 1);
            __syncthreads();
            int c = sc;
            __syncthreads();
            if (c >= PCH) break;
            hist_chunk(q, c, tid, dst, deg);
        }
    }
}

__global__ __launch_bounds__(1024) void k_scan1(const int* __restrict__ deg,
                                                int* loc, int* bsum){
    __shared__ int sd[1024];
    int b = blockIdx.x, tid = threadIdx.x, g = b*1024 + tid;
    int v = (g < NN) ? deg[g] : 0;
    sd[tid] = v;
    __syncthreads();
    for (int off = 1; off < 1024; off <<= 1){
        int t = (tid >= off) ? sd[tid-off] : 0;
        __syncthreads();
        sd[tid] += t;
        __syncthreads();
    }
    if (g < NN) loc[g] = sd[tid] - v;
    if (tid == 1023) bsum[b] = sd[1023];
}

// scan of 49 chunk sums (single wave) + zero dummy h rows
__global__ void k_scan2(int* bsum, float* h0, float* h1){
    int tid = threadIdx.x;
    int orig = (tid < NB_SCAN) ? bsum[tid] : 0;
    int v = orig;
    for (int off = 1; off < 64; off <<= 1){
        int t = __shfl_up(v, off);
        if (tid >= off) v += t;
    }
    if (tid < NB_SCAN) bsum[tid] = v - orig;
    h0[(size_t)NN*HIDC + tid] = 0.f;  h0[(size_t)NN*HIDC + 64 + tid] = 0.f;
    h1[(size_t)NN*HIDC + tid] = 0.f;  h1[(size_t)NN*HIDC + 64 + tid] = 0.f;
}

__global__ void k_scan3(const int* __restrict__ deg, const int* __restrict__ loc,
                        const int* __restrict__ bsum,
                        int* row_ptr, int* fill_pos, float* inv_deg){
    int g = blockIdx.x*blockDim.x + threadIdx.x;
    if (g < NN){
        int e = loc[g] + bsum[g >> 10];
        row_ptr[g] = e; fill_pos[g] = e;
        inv_deg[g] = 1.0f / (float)max(deg[g], 1);
    }
    if (g == 0) row_ptr[NN] = NE;
}

__device__ __forceinline__ void fill_chunk(int p, int c, int tid,
                                           const int* __restrict__ src,
                                           const int* __restrict__ dst,
                                           int* __restrict__ fill_pos,
                                           int* __restrict__ col){
    int lo = p*PSZ, hi = lo + PSZ;
    int e0 = c*ECH;
    for (int i = e0 + tid*4; i < e0 + ECH; i += 1024){
        int4 d4 = *(const int4*)(dst + i);
        if (d4.x >= lo && d4.x < hi){ int q = atomicAdd(&fill_pos[d4.x],1); col[q] = src[i+0]; }
        if (d4.y >= lo && d4.y < hi){ int q = atomicAdd(&fill_pos[d4.y],1); col[q] = src[i+1]; }
        if (d4.z >= lo && d4.z < hi){ int q = atomicAdd(&fill_pos[d4.z],1); col[q] = src[i+2]; }
        if (d4.w >= lo && d4.w < hi){ int q = atomicAdd(&fill_pos[d4.w],1); col[q] = src[i+3]; }
    }
}

__global__ __launch_bounds__(256) void k_fill_steal(
    const int* __restrict__ src, const int* __restrict__ dst,
    int* __restrict__ fill_pos, int* __restrict__ col,
    int* __restrict__ cnt)
{
    __shared__ int sc;
    int tid = threadIdx.x;
    int p = xcc_id();
    for(;;){
        if (tid == 0) sc = atomicAdd(&cnt[p], 1);
        __syncthreads();
        int c = sc;
        __syncthreads();
        if (c >= PCH) break;
        fill_chunk(p, c, tid, src, dst, fill_pos, col);
    }
    for (int q = 0; q < NXCD; q++){
        for(;;){
            if (tid == 0) sc = atomicAdd(&cnt[q], 1);
            __syncthreads();
            int c = sc;
            __syncthreads();
            if (c >= PCH) break;
            fill_chunk(q, c, tid, src, dst, fill_pos, col);
        }
    }
}

// gather-mean: one wave per node (lane = feature)
__global__ __launch_bounds__(256) void k_agg(
    const float* __restrict__ h_in,
    const int* __restrict__ row_ptr, const int* __restrict__ col,
    const float* __restrict__ inv_deg,
    float* __restrict__ agg)
{
    int tid = threadIdx.x;
    int wv = tid >> 6, f = tid & 63;
    int g = f >> 4, qoff = (f & 15) * 4;
    for (int node = blockIdx.x*4 + wv; node < NN; node += gridDim.x*4){
        int s0 = row_ptr[node], s1 = row_ptr[node+1];
        float a0 = 0.f, a1 = 0.f, a2 = 0.f, a3 = 0.f;
        for (int p0 = s0; p0 < s1; p0 += 64){
            int cnt = s1 - p0; if (cnt > 64) cnt = 64;
            int cidx = (f < cnt) ? col[p0 + f] : NN;   // NN -> zero row
            int nq = (cnt + 3) >> 2;
            for (int t = 0; t < nq; t++){
                int sidx = __shfl(cidx, t*4 + g);
                float4 v = *(const float4*)&h_in[(size_t)sidx*HIDC + qoff];
                a0 += v.x; a1 += v.y; a2 += v.z; a3 += v.w;
            }
        }
        a0 += __shfl_xor(a0, 16); a0 += __shfl_xor(a0, 32);
        a1 += __shfl_xor(a1, 16); a1 += __shfl_xor(a1, 32);
        a2 += __shfl_xor(a2, 16); a2 += __shfl_xor(a2, 32);
        a3 += __shfl_xor(a3, 16); a3 += __shfl_xor(a3, 32);
        if (g == 0){
            float idg = inv_deg[node];
            float4 o = make_float4(a0*idg, a1*idg, a2*idg, a3*idg);
            *(float4*)&agg[(size_t)node*HIDC + qoff] = o;
        }
    }
}

// ---- per-tile GEMM kernels: 512 threads = 8 waves = 8 f-chunks (8 outs
// each) of one 64-node tile -> 6256 waves total (24/CU) for latency hiding.
// lane = node; fb via readfirstlane -> s_load weights (round-6 lesson). ----

__global__ __launch_bounds__(512) void k_enc(
    const float* __restrict__ x,
    const float* __restrict__ w1, const float* __restrict__ b1,
    const float* __restrict__ w2, const float* __restrict__ b2,
    float* __restrict__ h)
{
    __shared__ float tl[64*64];
    int tile = blockIdx.x;
    int tid = threadIdx.x, lane = tid & 63;
    int fb = __builtin_amdgcn_readfirstlane((tid >> 6) * 8);
    int node = tile*64 + lane;
    int nc = (node < NN) ? node : (NN-1);     // x has exactly NN rows
    int sw = lane & 31;
    float out[8];
    #pragma unroll
    for (int j = 0; j < 8; j++) out[j] = b1[fb + j];
    gemm_acc8<2>(x + (size_t)nc*INC, w1, fb, out);
    #pragma unroll
    for (int j = 0; j < 8; j++)
        tl[lane*64 + ((fb + j) ^ sw)] = gelu_exact(out[j]);
    __syncthreads();
    float o2[8];
    #pragma unroll
    for (int j = 0; j < 8; j++) o2[j] = b2[fb + j];
    #pragma unroll 8
    for (int k = 0; k < HIDC; k++){
        float ink = tl[lane*64 + (k ^ sw)];
        const float* wr = w2 + (size_t)k*HIDC + fb;
        #pragma unroll
        for (int j = 0; j < 8; j++) o2[j] = fmaf(ink, wr[j], o2[j]);
    }
    if (node < NN){
        float* dst = h + (size_t)node*HIDC + fb;
        *(float4*)(dst + 0) = make_float4(o2[0], o2[1], o2[2], o2[3]);
        *(float4*)(dst + 4) = make_float4(o2[4], o2[5], o2[6], o2[7]);
    }
}

__global__ __launch_bounds__(512) void k_sage8(
    const float* __restrict__ h_in, const float* __restrict__ agg,
    const float* __restrict__ wl, const float* __restrict__ wr,
    const float* __restrict__ bias, float* __restrict__ h_out)
{
    int tile = blockIdx.x;
    int tid = threadIdx.x, lane = tid & 63;
    int fb = __builtin_amdgcn_readfirstlane((tid >> 6) * 8);
    int node = tile*64 + lane;                 // buffers padded to NPAD rows
    float out[8];
    #pragma unroll
    for (int j = 0; j < 8; j++) out[j] = bias[fb + j];
    gemm_acc8<4>(agg  + (size_t)node*HIDC, wl, fb, out);
    gemm_acc8<4>(h_in + (size_t)node*HIDC, wr, fb, out);
    if (node < NN){
        float* dst = h_out + (size_t)node*HIDC + fb;
        *(float4*)(dst + 0) = make_float4(gelu_exact(out[0]), gelu_exact(out[1]),
                                          gelu_exact(out[2]), gelu_exact(out[3]));
        *(float4*)(dst + 4) = make_float4(gelu_exact(out[4]), gelu_exact(out[5]),
                                          gelu_exact(out[6]), gelu_exact(out[7]));
    }
}

__global__ __launch_bounds__(512) void k_dec1(
    const float* __restrict__ h, const float* __restrict__ w1,
    const float* __restrict__ b1, float* __restrict__ tbuf)
{
    int tile = blockIdx.x;
    int tid = threadIdx.x, lane = tid & 63;
    int fb = __builtin_amdgcn_readfirstlane((tid >> 6) * 8);
    int node = tile*64 + lane;
    float out[8];
    #pragma unroll
    for (int j = 0; j < 8; j++) out[j] = b1[fb + j];
    gemm_acc8<4>(h + (size_t)node*HIDC, w1, fb, out);
    float* dst = tbuf + (size_t)node*HIDC + fb;   // tbuf padded: unmasked
    *(float4*)(dst + 0) = make_float4(gelu_exact(out[0]), gelu_exact(out[1]),
                                      gelu_exact(out[2]), gelu_exact(out[3]));
    *(float4*)(dst + 4) = make_float4(gelu_exact(out[4]), gelu_exact(out[5]),
                                      gelu_exact(out[6]), gelu_exact(out[7]));
}

__global__ __launch_bounds__(256) void k_dec2(
    const float* __restrict__ tbuf, const float* __restrict__ w2,
    const float* __restrict__ b2, float* __restrict__ out)
{
    int tile = blockIdx.x*4 + (threadIdx.x >> 6);
    if (tile >= NT_TILES) return;              // wave-uniform branch
    int lane = threadIdx.x & 63;
    int node = tile*64 + lane;
    const float* inrow = tbuf + (size_t)node*HIDC;
    float o[OUTC];
    #pragma unroll
    for (int j = 0; j < OUTC; j++) o[j] = b2[j];
    #pragma unroll 2
    for (int kc = 0; kc < 4; kc++){
        float4 q0 = *(const float4*)(inrow + kc*16 + 0);
        float4 q1 = *(const float4*)(inrow + kc*16 + 4);
        float4 q2 = *(const float4*)(inrow + kc*16 + 8);
        float4 q3 = *(const float4*)(inrow + kc*16 + 12);
        float in16[16] = {q0.x,q0.y,q0.z,q0.w, q1.x,q1.y,q1.z,q1.w,
                          q2.x,q2.y,q2.z,q2.w, q3.x,q3.y,q3.z,q3.w};
        #pragma unroll
        for (int kk = 0; kk < 16; kk++){
            const float* wr = w2 + (size_t)(kc*16+kk)*OUTC;
            #pragma unroll
            for (int j = 0; j < OUTC; j++)
                o[j] = fmaf(in16[kk], wr[j], o[j]);
        }
    }
    if (node < NN){
        *(float4*)(out + (size_t)node*OUTC + 0) = make_float4(o[0],o[1],o[2],o[3]);
        *(float4*)(out + (size_t)node*OUTC + 4) = make_float4(o[4],o[5],o[6],o[7]);
    }
}

extern "C" void kernel_launch(void* const* d_in, const int* in_sizes, int n_in,
                              void* d_out, int out_size, void* d_ws, size_t ws_size,
                              hipStream_t stream){
    const float* x      = (const float*)d_in[0];
    const int*   ei     = (const int*)  d_in[1];
    const float* enc_w1 = (const float*)d_in[2];
    const float* enc_b1 = (const float*)d_in[3];
    const float* enc_w2 = (const float*)d_in[4];
    const float* enc_b2 = (const float*)d_in[5];
    const float* sage_wl= (const float*)d_in[6];
    const float* sage_wr= (const float*)d_in[7];
    const float* sage_b = (const float*)d_in[8];
    const float* dec_w1 = (const float*)d_in[9];
    const float* dec_b1 = (const float*)d_in[10];
    const float* dec_w2 = (const float*)d_in[11];
    const float* dec_b2 = (const float*)d_in[12];
    float* out = (float*)d_out;

    char* ws = (char*)d_ws;
    size_t off = 0;
    auto alloc = [&](size_t bytes)->void*{
        void* p = ws + off; off = (off + bytes + 255) & ~(size_t)255; return p;
    };
    int*   deg      = (int*)  alloc((size_t)NN*4);
    int*   loc      = (int*)  alloc((size_t)NN*4);
    int*   bsum     = (int*)  alloc(64*4);
    int*   cnt      = (int*)  alloc(16*4);     // [0..7] hist, [8..15] fill
    int*   row_ptr  = (int*)  alloc((size_t)(NN+1)*4);
    int*   fill_pos = (int*)  alloc((size_t)NN*4);
    int*   col      = (int*)  alloc((size_t)NE*4);
    float* inv_deg  = (float*)alloc((size_t)NN*4);
    float* h0       = (float*)alloc((size_t)NPAD*HIDC*4);
    float* h1       = (float*)alloc((size_t)NPAD*HIDC*4);
    float* agg      = (float*)alloc((size_t)NPAD*HIDC*4);  // doubles as tbuf

    const int* srcv = ei;        // edge_index row 0
    const int* dstv = ei + NE;   // edge_index row 1

    hipMemsetAsync(deg, 0, (size_t)NN*4, stream);
    hipMemsetAsync(cnt, 0, 16*4, stream);
    hipLaunchKernelGGL(k_hist_steal, dim3(256), dim3(256), 0, stream,
                       dstv, deg, cnt);
    hipLaunchKernelGGL(k_scan1, dim3(NB_SCAN), dim3(1024), 0, stream, deg, loc, bsum);
    hipLaunchKernelGGL(k_scan2, dim3(1),       dim3(64),   0, stream, bsum, h0, h1);
    hipLaunchKernelGGL(k_scan3, dim3((NN+255)/256), dim3(256), 0, stream,
                       deg, loc, bsum, row_ptr, fill_pos, inv_deg);
    hipLaunchKernelGGL(k_fill_steal, dim3(256), dim3(256), 0, stream,
                       srcv, dstv, fill_pos, col, cnt + 8);

    hipLaunchKernelGGL(k_enc, dim3(NT_TILES), dim3(512), 0, stream,
                       x, enc_w1, enc_b1, enc_w2, enc_b2, h0);

    const float* hin = h0; float* hout = h1;
    for (int l = 0; l < 3; l++){
        hipLaunchKernelGGL(k_agg, dim3(2048), dim3(256), 0, stream,
                           hin, row_ptr, col, inv_deg, agg);
        hipLaunchKernelGGL(k_sage8, dim3(NT_TILES), dim3(512), 0, stream,
                           hin, agg,
                           sage_wl + (size_t)l*HIDC*HIDC,
                           sage_wr + (size_t)l*HIDC*HIDC,
                           sage_b  + (size_t)l*HIDC,
                           hout);
        float* t = (float*)hin; hin = hout; hout = t;
    }

    hipLaunchKernelGGL(k_dec1, dim3(NT_TILES),       dim3(512), 0, stream,
                       hin, dec_w1, dec_b1, agg);
    hipLaunchKernelGGL(k_dec2, dim3((NT_TILES+3)/4), dim3(256), 0, stream,
                       agg, dec_w2, dec_b2, out);
}

// Round 11
// 357.973 us; speedup vs baseline: 2.3268x; 2.3268x over previous
//
#include <hip/hip_runtime.h>
#include <math.h>

#define NN 50000
#define NE 800000
#define INC 32
#define HIDC 64
#define OUTC 8
#define NB_SCAN ((NN + 1023) / 1024)   // 49
#define NT_TILES ((NN + 63) / 64)      // 782
#define NPAD (NT_TILES * 64)           // 50048 padded rows
#define NXCD 8
#define PCH 32                          // edge chunks per partition
#define PSZ ((NN + NXCD - 1) / NXCD)    // 6250 dsts per partition
#define ECH (NE / PCH)                  // 25000 edges per chunk (4-aligned)
#define AS 68                           // LDS stride for 64-wide tiles (16B-aligned rows)
#define XS 36                           // LDS stride for 32-wide x tile

__device__ __forceinline__ float gelu_exact(float x){
    return 0.5f * x * (1.0f + erff(x * 0.70710678118654752f));
}

__device__ __forceinline__ int xcc_id(){
    int x;
    asm volatile("s_getreg_b32 %0, hwreg(HW_REG_XCC_ID)" : "=s"(x));
    return x & (NXCD-1);
}

// register-tiled 4x4 GEMM inner loop: acc[r][c] += At[m0+r][k] * Ws[k][n0+c]
// At: LDS, stride ST. Ws: LDS, row-major [KK][HIDC]. All reads <=2-way (free).
template<int ST, int KK>
__device__ __forceinline__ void mm_tile(const float* __restrict__ At,
                                        const float* __restrict__ Ws,
                                        int m0, int n0, float acc[4][4])
{
    #pragma unroll 2
    for (int k = 0; k < KK; k += 2){
        float2 av[4];
        #pragma unroll
        for (int r = 0; r < 4; r++)
            av[r] = *(const float2*)&At[(m0+r)*ST + k];
        float4 w0 = *(const float4*)&Ws[(k+0)*HIDC + n0];
        float4 w1 = *(const float4*)&Ws[(k+1)*HIDC + n0];
        #pragma unroll
        for (int r = 0; r < 4; r++){
            acc[r][0] = fmaf(av[r].x, w0.x, acc[r][0]);
            acc[r][1] = fmaf(av[r].x, w0.y, acc[r][1]);
            acc[r][2] = fmaf(av[r].x, w0.z, acc[r][2]);
            acc[r][3] = fmaf(av[r].x, w0.w, acc[r][3]);
            acc[r][0] = fmaf(av[r].y, w1.x, acc[r][0]);
            acc[r][1] = fmaf(av[r].y, w1.y, acc[r][1]);
            acc[r][2] = fmaf(av[r].y, w1.z, acc[r][2]);
            acc[r][3] = fmaf(av[r].y, w1.w, acc[r][3]);
        }
    }
}

// ---- CSR build: XCC-affine work claiming (real XCD id + steal sweep) ----

__device__ __forceinline__ void hist_chunk(int p, int c, int tid,
                                           const int* __restrict__ dst,
                                           int* __restrict__ deg){
    int lo = p*PSZ, hi = lo + PSZ;
    int e0 = c*ECH;
    for (int i = e0 + tid*4; i < e0 + ECH; i += 1024){
        int4 d4 = *(const int4*)(dst + i);
        if (d4.x >= lo && d4.x < hi) atomicAdd(&deg[d4.x], 1);
        if (d4.y >= lo && d4.y < hi) atomicAdd(&deg[d4.y], 1);
        if (d4.z >= lo && d4.z < hi) atomicAdd(&deg[d4.z], 1);
        if (d4.w >= lo && d4.w < hi) atomicAdd(&deg[d4.w], 1);
    }
}

__global__ __launch_bounds__(256) void k_hist_steal(const int* __restrict__ dst,
                                                    int* __restrict__ deg,
                                                    int* __restrict__ cnt){
    __shared__ int sc;
    int tid = threadIdx.x;
    int p = xcc_id();
    for(;;){
        if (tid == 0) sc = atomicAdd(&cnt[p], 1);
        __syncthreads();
        int c = sc;
        __syncthreads();
        if (c >= PCH) break;
        hist_chunk(p, c, tid, dst, deg);
    }
    for (int q = 0; q < NXCD; q++){
        for(;;){
            if (tid == 0) sc = atomicAdd(&cnt[q], 1);
            __syncthreads();
            int c = sc;
            __syncthreads();
            if (c >= PCH) break;
            hist_chunk(q, c, tid, dst, deg);
        }
    }
}

__global__ __launch_bounds__(1024) void k_scan1(const int* __restrict__ deg,
                                                int* loc, int* bsum){
    __shared__ int sd[1024];
    int b = blockIdx.x, tid = threadIdx.x, g = b*1024 + tid;
    int v = (g < NN) ? deg[g] : 0;
    sd[tid] = v;
    __syncthreads();
    for (int off = 1; off < 1024; off <<= 1){
        int t = (tid >= off) ? sd[tid-off] : 0;
        __syncthreads();
        sd[tid] += t;
        __syncthreads();
    }
    if (g < NN) loc[g] = sd[tid] - v;
    if (tid == 1023) bsum[b] = sd[1023];
}

__global__ void k_scan2(int* bsum, float* h0, float* h1){
    int tid = threadIdx.x;
    int orig = (tid < NB_SCAN) ? bsum[tid] : 0;
    int v = orig;
    for (int off = 1; off < 64; off <<= 1){
        int t = __shfl_up(v, off);
        if (tid >= off) v += t;
    }
    if (tid < NB_SCAN) bsum[tid] = v - orig;
    h0[(size_t)NN*HIDC + tid] = 0.f;  h0[(size_t)NN*HIDC + 64 + tid] = 0.f;
    h1[(size_t)NN*HIDC + tid] = 0.f;  h1[(size_t)NN*HIDC + 64 + tid] = 0.f;
}

__global__ void k_scan3(const int* __restrict__ deg, const int* __restrict__ loc,
                        const int* __restrict__ bsum,
                        int* row_ptr, int* fill_pos, float* inv_deg){
    int g = blockIdx.x*blockDim.x + threadIdx.x;
    if (g < NN){
        int e = loc[g] + bsum[g >> 10];
        row_ptr[g] = e; fill_pos[g] = e;
        inv_deg[g] = 1.0f / (float)max(deg[g], 1);
    }
    if (g == 0) row_ptr[NN] = NE;
}

__device__ __forceinline__ void fill_chunk(int p, int c, int tid,
                                           const int* __restrict__ src,
                                           const int* __restrict__ dst,
                                           int* __restrict__ fill_pos,
                                           int* __restrict__ col){
    int lo = p*PSZ, hi = lo + PSZ;
    int e0 = c*ECH;
    for (int i = e0 + tid*4; i < e0 + ECH; i += 1024){
        int4 d4 = *(const int4*)(dst + i);
        if (d4.x >= lo && d4.x < hi){ int q = atomicAdd(&fill_pos[d4.x],1); col[q] = src[i+0]; }
        if (d4.y >= lo && d4.y < hi){ int q = atomicAdd(&fill_pos[d4.y],1); col[q] = src[i+1]; }
        if (d4.z >= lo && d4.z < hi){ int q = atomicAdd(&fill_pos[d4.z],1); col[q] = src[i+2]; }
        if (d4.w >= lo && d4.w < hi){ int q = atomicAdd(&fill_pos[d4.w],1); col[q] = src[i+3]; }
    }
}

__global__ __launch_bounds__(256) void k_fill_steal(
    const int* __restrict__ src, const int* __restrict__ dst,
    int* __restrict__ fill_pos, int* __restrict__ col,
    int* __restrict__ cnt)
{
    __shared__ int sc;
    int tid = threadIdx.x;
    int p = xcc_id();
    for(;;){
        if (tid == 0) sc = atomicAdd(&cnt[p], 1);
        __syncthreads();
        int c = sc;
        __syncthreads();
        if (c >= PCH) break;
        fill_chunk(p, c, tid, src, dst, fill_pos, col);
    }
    for (int q = 0; q < NXCD; q++){
        for(;;){
            if (tid == 0) sc = atomicAdd(&cnt[q], 1);
            __syncthreads();
            int c = sc;
            __syncthreads();
            if (c >= PCH) break;
            fill_chunk(q, c, tid, src, dst, fill_pos, col);
        }
    }
}

// gather-mean: one wave per node (lane = feature)
__global__ __launch_bounds__(256) void k_agg(
    const float* __restrict__ h_in,
    const int* __restrict__ row_ptr, const int* __restrict__ col,
    const float* __restrict__ inv_deg,
    float* __restrict__ agg)
{
    int tid = threadIdx.x;
    int wv = tid >> 6, f = tid & 63;
    int g = f >> 4, qoff = (f & 15) * 4;
    for (int node = blockIdx.x*4 + wv; node < NN; node += gridDim.x*4){
        int s0 = row_ptr[node], s1 = row_ptr[node+1];
        float a0 = 0.f, a1 = 0.f, a2 = 0.f, a3 = 0.f;
        for (int p0 = s0; p0 < s1; p0 += 64){
            int cnt = s1 - p0; if (cnt > 64) cnt = 64;
            int cidx = (f < cnt) ? col[p0 + f] : NN;   // NN -> zero row
            int nq = (cnt + 3) >> 2;
            for (int t = 0; t < nq; t++){
                int sidx = __shfl(cidx, t*4 + g);
                float4 v = *(const float4*)&h_in[(size_t)sidx*HIDC + qoff];
                a0 += v.x; a1 += v.y; a2 += v.z; a3 += v.w;
            }
        }
        a0 += __shfl_xor(a0, 16); a0 += __shfl_xor(a0, 32);
        a1 += __shfl_xor(a1, 16); a1 += __shfl_xor(a1, 32);
        a2 += __shfl_xor(a2, 16); a2 += __shfl_xor(a2, 32);
        a3 += __shfl_xor(a3, 16); a3 += __shfl_xor(a3, 32);
        if (g == 0){
            float idg = inv_deg[node];
            float4 o = make_float4(a0*idg, a1*idg, a2*idg, a3*idg);
            *(float4*)&agg[(size_t)node*HIDC + qoff] = o;
        }
    }
}

// ---- register-tiled LDS GEMM kernels: one 64-node tile per 256-thread
// block; thread = 4 nodes x 4 cols; weights + A-tile in LDS. ----

// encoder: h = gelu(x@w1+b1)@w2+b2 ; T lives in LDS between phases
__global__ __launch_bounds__(256) void k_enc(
    const float* __restrict__ x,
    const float* __restrict__ w1, const float* __restrict__ b1,
    const float* __restrict__ w2, const float* __restrict__ b2,
    float* __restrict__ h)
{
    __shared__ float w1s[INC*HIDC];
    __shared__ float w2s[HIDC*HIDC];
    __shared__ float Xt[64*XS];
    __shared__ float T[64*AS];
    int tid = threadIdx.x, tile = blockIdx.x;
    for (int i = tid*4; i < INC*HIDC;  i += 1024)
        *(float4*)&w1s[i] = *(const float4*)&w1[i];
    for (int i = tid*4; i < HIDC*HIDC; i += 1024)
        *(float4*)&w2s[i] = *(const float4*)&w2[i];
    for (int i = tid*4; i < 64*INC; i += 1024){
        int m = i >> 5, k = i & 31;
        int row = tile*64 + m; if (row >= NN) row = NN-1;   // x has NN rows
        *(float4*)&Xt[m*XS + k] = *(const float4*)&x[(size_t)row*INC + k];
    }
    __syncthreads();
    int tx = tid & 15, ty = tid >> 4;
    int m0 = ty*4, n0 = tx*4;
    float4 b1v = *(const float4*)&b1[n0];
    float acc[4][4];
    #pragma unroll
    for (int r = 0; r < 4; r++){
        acc[r][0]=b1v.x; acc[r][1]=b1v.y; acc[r][2]=b1v.z; acc[r][3]=b1v.w;
    }
    mm_tile<XS, INC>(Xt, w1s, m0, n0, acc);
    #pragma unroll
    for (int r = 0; r < 4; r++){
        float4 o = make_float4(gelu_exact(acc[r][0]), gelu_exact(acc[r][1]),
                               gelu_exact(acc[r][2]), gelu_exact(acc[r][3]));
        *(float4*)&T[(m0+r)*AS + n0] = o;
    }
    __syncthreads();
    float4 b2v = *(const float4*)&b2[n0];
    #pragma unroll
    for (int r = 0; r < 4; r++){
        acc[r][0]=b2v.x; acc[r][1]=b2v.y; acc[r][2]=b2v.z; acc[r][3]=b2v.w;
    }
    mm_tile<AS, HIDC>(T, w2s, m0, n0, acc);
    #pragma unroll
    for (int r = 0; r < 4; r++){
        int node = tile*64 + m0 + r;
        if (node < NN)
            *(float4*)&h[(size_t)node*HIDC + n0] =
                make_float4(acc[r][0], acc[r][1], acc[r][2], acc[r][3]);
    }
}

// sage: h_out = gelu(agg@wl + h_in@wr + b) ; two phases share one A-buffer
__global__ __launch_bounds__(256) void k_sage(
    const float* __restrict__ h_in, const float* __restrict__ agg,
    const float* __restrict__ wl, const float* __restrict__ wr,
    const float* __restrict__ bias, float* __restrict__ h_out)
{
    __shared__ float Wl[HIDC*HIDC];
    __shared__ float Wr[HIDC*HIDC];
    __shared__ float At[64*AS];
    int tid = threadIdx.x, tile = blockIdx.x;
    for (int i = tid*4; i < HIDC*HIDC; i += 1024){
        *(float4*)&Wl[i] = *(const float4*)&wl[i];
        *(float4*)&Wr[i] = *(const float4*)&wr[i];
    }
    const float* abase = agg + (size_t)tile*64*HIDC;    // padded to NPAD rows
    for (int i = tid*4; i < 64*HIDC; i += 1024){
        int m = i >> 6, k = i & 63;
        *(float4*)&At[m*AS + k] = *(const float4*)&abase[i];
    }
    __syncthreads();
    int tx = tid & 15, ty = tid >> 4;
    int m0 = ty*4, n0 = tx*4;
    float4 bv = *(const float4*)&bias[n0];
    float acc[4][4];
    #pragma unroll
    for (int r = 0; r < 4; r++){
        acc[r][0]=bv.x; acc[r][1]=bv.y; acc[r][2]=bv.z; acc[r][3]=bv.w;
    }
    mm_tile<AS, HIDC>(At, Wl, m0, n0, acc);
    __syncthreads();                                    // all reads of At done
    const float* hbase = h_in + (size_t)tile*64*HIDC;
    for (int i = tid*4; i < 64*HIDC; i += 1024){
        int m = i >> 6, k = i & 63;
        *(float4*)&At[m*AS + k] = *(const float4*)&hbase[i];
    }
    __syncthreads();
    mm_tile<AS, HIDC>(At, Wr, m0, n0, acc);
    #pragma unroll
    for (int r = 0; r < 4; r++){
        int node = tile*64 + m0 + r;
        if (node < NN)
            *(float4*)&h_out[(size_t)node*HIDC + n0] =
                make_float4(gelu_exact(acc[r][0]), gelu_exact(acc[r][1]),
                            gelu_exact(acc[r][2]), gelu_exact(acc[r][3]));
    }
}

// fused decoder: out = gelu(h@w1+b1)@w2+b2 ; T in LDS, 8 outputs/node
__global__ __launch_bounds__(256) void k_dec(
    const float* __restrict__ hbuf,
    const float* __restrict__ w1, const float* __restrict__ b1,
    const float* __restrict__ w2, const float* __restrict__ b2,
    float* __restrict__ out)
{
    __shared__ float w1s[HIDC*HIDC];
    __shared__ float w2s[HIDC*OUTC];
    __shared__ float At[64*AS];
    __shared__ float T[64*AS];
    int tid = threadIdx.x, tile = blockIdx.x;
    for (int i = tid*4; i < HIDC*HIDC; i += 1024)
        *(float4*)&w1s[i] = *(const float4*)&w1[i];
    if (tid*4 < HIDC*OUTC)
        *(float4*)&w2s[tid*4] = *(const float4*)&w2[tid*4];
    const float* hbase = hbuf + (size_t)tile*64*HIDC;
    for (int i = tid*4; i < 64*HIDC; i += 1024){
        int m = i >> 6, k = i & 63;
        *(float4*)&At[m*AS + k] = *(const float4*)&hbase[i];
    }
    __syncthreads();
    int tx = tid & 15, ty = tid >> 4;
    int m0 = ty*4, n0 = tx*4;
    float4 b1v = *(const float4*)&b1[n0];
    float acc[4][4];
    #pragma unroll
    for (int r = 0; r < 4; r++){
        acc[r][0]=b1v.x; acc[r][1]=b1v.y; acc[r][2]=b1v.z; acc[r][3]=b1v.w;
    }
    mm_tile<AS, HIDC>(At, w1s, m0, n0, acc);
    #pragma unroll
    for (int r = 0; r < 4; r++){
        float4 o = make_float4(gelu_exact(acc[r][0]), gelu_exact(acc[r][1]),
                               gelu_exact(acc[r][2]), gelu_exact(acc[r][3]));
        *(float4*)&T[(m0+r)*AS + n0] = o;
    }
    __syncthreads();
    // phase 2: node m = tid>>2 (0..63), cols c0,c0+1 with c0 = (tid&3)*2
    int m = tid >> 2, c0 = (tid & 3) * 2;
    float a0 = b2[c0], a1 = b2[c0+1];
    #pragma unroll 4
    for (int k = 0; k < HIDC; k++){
        float tv = T[m*AS + k];
        float2 wv = *(const float2*)&w2s[k*OUTC + c0];
        a0 = fmaf(tv, wv.x, a0);
        a1 = fmaf(tv, wv.y, a1);
    }
    int node = tile*64 + m;
    if (node < NN)
        *(float2*)&out[(size_t)node*OUTC + c0] = make_float2(a0, a1);
}

extern "C" void kernel_launch(void* const* d_in, const int* in_sizes, int n_in,
                              void* d_out, int out_size, void* d_ws, size_t ws_size,
                              hipStream_t stream){
    const float* x      = (const float*)d_in[0];
    const int*   ei     = (const int*)  d_in[1];
    const float* enc_w1 = (const float*)d_in[2];
    const float* enc_b1 = (const float*)d_in[3];
    const float* enc_w2 = (const float*)d_in[4];
    const float* enc_b2 = (const float*)d_in[5];
    const float* sage_wl= (const float*)d_in[6];
    const float* sage_wr= (const float*)d_in[7];
    const float* sage_b = (const float*)d_in[8];
    const float* dec_w1 = (const float*)d_in[9];
    const float* dec_b1 = (const float*)d_in[10];
    const float* dec_w2 = (const float*)d_in[11];
    const float* dec_b2 = (const float*)d_in[12];
    float* out = (float*)d_out;

    char* ws = (char*)d_ws;
    size_t off = 0;
    auto alloc = [&](size_t bytes)->void*{
        void* p = ws + off; off = (off + bytes + 255) & ~(size_t)255; return p;
    };
    int*   deg      = (int*)  alloc((size_t)NN*4);
    int*   loc      = (int*)  alloc((size_t)NN*4);
    int*   bsum     = (int*)  alloc(64*4);
    int*   cnt      = (int*)  alloc(16*4);     // [0..7] hist, [8..15] fill
    int*   row_ptr  = (int*)  alloc((size_t)(NN+1)*4);
    int*   fill_pos = (int*)  alloc((size_t)NN*4);
    int*   col      = (int*)  alloc((size_t)NE*4);
    float* inv_deg  = (float*)alloc((size_t)NN*4);
    float* h0       = (float*)alloc((size_t)NPAD*HIDC*4);
    float* h1       = (float*)alloc((size_t)NPAD*HIDC*4);
    float* agg      = (float*)alloc((size_t)NPAD*HIDC*4);

    const int* srcv = ei;        // edge_index row 0
    const int* dstv = ei + NE;   // edge_index row 1

    hipMemsetAsync(deg, 0, (size_t)NN*4, stream);
    hipMemsetAsync(cnt, 0, 16*4, stream);
    hipLaunchKernelGGL(k_hist_steal, dim3(256), dim3(256), 0, stream,
                       dstv, deg, cnt);
    hipLaunchKernelGGL(k_scan1, dim3(NB_SCAN), dim3(1024), 0, stream, deg, loc, bsum);
    hipLaunchKernelGGL(k_scan2, dim3(1),       dim3(64),   0, stream, bsum, h0, h1);
    hipLaunchKernelGGL(k_scan3, dim3((NN+255)/256), dim3(256), 0, stream,
                       deg, loc, bsum, row_ptr, fill_pos, inv_deg);
    hipLaunchKernelGGL(k_fill_steal, dim3(256), dim3(256), 0, stream,
                       srcv, dstv, fill_pos, col, cnt + 8);

    hipLaunchKernelGGL(k_enc, dim3(NT_TILES), dim3(256), 0, stream,
                       x, enc_w1, enc_b1, enc_w2, enc_b2, h0);

    const float* hin = h0; float* hout = h1;
    for (int l = 0; l < 3; l++){
        hipLaunchKernelGGL(k_agg, dim3(2048), dim3(256), 0, stream,
                           hin, row_ptr, col, inv_deg, agg);
        hipLaunchKernelGGL(k_sage, dim3(NT_TILES), dim3(256), 0, stream,
                           hin, agg,
                           sage_wl + (size_t)l*HIDC*HIDC,
                           sage_wr + (size_t)l*HIDC*HIDC,
                           sage_b  + (size_t)l*HIDC,
                           hout);
        float* t = (float*)hin; hin = hout; hout = t;
    }

    hipLaunchKernelGGL(k_dec, dim3(NT_TILES), dim3(256), 0, stream,
                       hin, dec_w1, dec_b1, dec_w2, dec_b2, out);
}

// Round 12
// 243.888 us; speedup vs baseline: 3.4152x; 1.4678x over previous
//
#include <hip/hip_runtime.h>
#include <math.h>

#define NN 50000
#define NE 800000
#define INC 32
#define HIDC 64
#define OUTC 8
#define NT_TILES ((NN + 63) / 64)      // 782
#define NPAD (NT_TILES * 64)           // 50048 padded rows
#define AS 68                           // LDS stride for 64-wide tiles
#define XS 36                           // LDS stride for 32-wide x tile
#define NCH 250                         // edge chunks (level 0 blocks)
#define ECHK (NE / NCH)                 // 3200 edges per chunk
#define NBK2 196                        // coarse buckets = ceil(NN/256)

__device__ __forceinline__ float gelu_exact(float x){
    return 0.5f * x * (1.0f + erff(x * 0.70710678118654752f));
}

// register-tiled 4x4 GEMM inner loop: acc[r][c] += At[m0+r][k] * Ws[k][n0+c]
template<int ST, int KK>
__device__ __forceinline__ void mm_tile(const float* __restrict__ At,
                                        const float* __restrict__ Ws,
                                        int m0, int n0, float acc[4][4])
{
    #pragma unroll 2
    for (int k = 0; k < KK; k += 2){
        float2 av[4];
        #pragma unroll
        for (int r = 0; r < 4; r++)
            av[r] = *(const float2*)&At[(m0+r)*ST + k];
        float4 w0 = *(const float4*)&Ws[(k+0)*HIDC + n0];
        float4 w1 = *(const float4*)&Ws[(k+1)*HIDC + n0];
        #pragma unroll
        for (int r = 0; r < 4; r++){
            acc[r][0] = fmaf(av[r].x, w0.x, acc[r][0]);
            acc[r][1] = fmaf(av[r].x, w0.y, acc[r][1]);
            acc[r][2] = fmaf(av[r].x, w0.z, acc[r][2]);
            acc[r][3] = fmaf(av[r].x, w0.w, acc[r][3]);
            acc[r][0] = fmaf(av[r].y, w1.x, acc[r][0]);
            acc[r][1] = fmaf(av[r].y, w1.y, acc[r][1]);
            acc[r][2] = fmaf(av[r].y, w1.z, acc[r][2]);
            acc[r][3] = fmaf(av[r].y, w1.w, acc[r][3]);
        }
    }
}

// ---- CSR build, two-level bucket sort. No scattered global stores:
// every output region has exactly ONE writer block (rounds 5-11 lesson:
// scattered 4B stores cost a 32B sector each -> 10-16x write amplification,
// and single-block-owns-everything collapses parallelism). ----

// level 0: bin each 3200-edge chunk by coarse bucket (dst>>8) into the
// chunk's private region of ebuf; record per-(chunk,bucket) counts+offsets.
__global__ __launch_bounds__(256) void k_ebin(
    const int* __restrict__ src, const int* __restrict__ dst,
    int2* __restrict__ ebuf, int* __restrict__ cnts, int* __restrict__ lboff)
{
    __shared__ int cnt[256];
    __shared__ int cur[256];
    int c = blockIdx.x, tid = threadIdx.x;
    cnt[tid] = 0;
    __syncthreads();
    int e0 = c*ECHK;
    for (int i = e0 + tid; i < e0 + ECHK; i += 256)
        atomicAdd(&cnt[dst[i] >> 8], 1);
    __syncthreads();
    int v = cnt[tid];
    for (int off = 1; off < 256; off <<= 1){
        int t = (tid >= off) ? cnt[tid-off] : 0;
        __syncthreads();
        cnt[tid] += t;
        __syncthreads();
    }
    int excl = cnt[tid] - v;
    if (tid < NBK2){
        cnts[c*NBK2 + tid]  = v;
        lboff[c*NBK2 + tid] = excl;
    }
    cur[tid] = excl;
    __syncthreads();
    for (int i = e0 + tid; i < e0 + ECHK; i += 256){
        int d = dst[i], s = src[i];
        int p = atomicAdd(&cur[d >> 8], 1);
        ebuf[e0 + p] = make_int2(d, s);
    }
}

// level 0.5: per-bucket exclusive prefix over the 250 chunk counts
__global__ __launch_bounds__(256) void k_choff(
    const int* __restrict__ cnts, int* __restrict__ choff, int* __restrict__ btot)
{
    __shared__ int sd[256];
    int b = blockIdx.x, tid = threadIdx.x;
    int v = (tid < NCH) ? cnts[tid*NBK2 + b] : 0;
    sd[tid] = v;
    __syncthreads();
    for (int off = 1; off < 256; off <<= 1){
        int t = (tid >= off) ? sd[tid-off] : 0;
        __syncthreads();
        sd[tid] += t;
        __syncthreads();
    }
    if (tid < NCH) choff[b*NCH + tid] = sd[tid] - v;
    if (tid == 255) btot[b] = sd[255];
}

// bucket bases + misc init (dummy rows, row_ptr[NN])
__global__ __launch_bounds__(256) void k_bbase(
    const int* __restrict__ btot, int* __restrict__ bbase,
    float* h0, float* h1, int* row_ptr)
{
    __shared__ int sd[256];
    int tid = threadIdx.x;
    int v = (tid < NBK2) ? btot[tid] : 0;
    sd[tid] = v;
    __syncthreads();
    for (int off = 1; off < 256; off <<= 1){
        int t = (tid >= off) ? sd[tid-off] : 0;
        __syncthreads();
        sd[tid] += t;
        __syncthreads();
    }
    if (tid < NBK2) bbase[tid] = sd[tid] - v;
    if (tid == 0) row_ptr[NN] = NE;
    if (tid < 64){
        h0[(size_t)NN*HIDC + tid] = 0.f;
        h1[(size_t)NN*HIDC + tid] = 0.f;
    }
}

// level 1: block b owns bucket b (256 dsts): fine histogram + scan ->
// row_ptr/inv_deg slices, then scatter src into the bucket's private col
// region via LDS cursors. Flattened edge loop via binary search over the
// chunk-prefix table (no per-chunk serial iteration -> round-8 lesson).
__global__ __launch_bounds__(256) void k_bsort(
    const int2* __restrict__ ebuf, const int* __restrict__ lboff,
    const int* __restrict__ choff, const int* __restrict__ btot,
    const int* __restrict__ bbase,
    int* __restrict__ row_ptr, int* __restrict__ col,
    float* __restrict__ inv_deg)
{
    __shared__ int cum[NCH];
    __shared__ int lb[NCH];
    __shared__ int hcnt[256];
    __shared__ int fpos[256];
    int b = blockIdx.x, tid = threadIdx.x;
    if (tid < NCH){
        cum[tid] = choff[b*NCH + tid];
        lb[tid]  = lboff[tid*NBK2 + b];
    }
    hcnt[tid] = 0;
    __syncthreads();
    int tot = btot[b];
    int lo = b << 8;
    for (int e = tid; e < tot; e += 256){
        int lc = 0, hc = NCH;
        while (hc - lc > 1){ int mid = (lc+hc) >> 1; if (cum[mid] <= e) lc = mid; else hc = mid; }
        int2 pr = ebuf[lc*ECHK + lb[lc] + (e - cum[lc])];
        atomicAdd(&hcnt[pr.x - lo], 1);
    }
    __syncthreads();
    int v = hcnt[tid];
    for (int off = 1; off < 256; off <<= 1){
        int t = (tid >= off) ? hcnt[tid-off] : 0;
        __syncthreads();
        hcnt[tid] += t;
        __syncthreads();
    }
    int excl = hcnt[tid] - v;
    int base = bbase[b];
    int g = lo + tid;
    if (g < NN){
        row_ptr[g] = base + excl;
        inv_deg[g] = 1.0f / (float)max(v, 1);
    }
    fpos[tid] = base + excl;
    __syncthreads();
    for (int e = tid; e < tot; e += 256){
        int lc = 0, hc = NCH;
        while (hc - lc > 1){ int mid = (lc+hc) >> 1; if (cum[mid] <= e) lc = mid; else hc = mid; }
        int2 pr = ebuf[lc*ECHK + lb[lc] + (e - cum[lc])];
        int q = atomicAdd(&fpos[pr.x - lo], 1);
        col[q] = pr.y;
    }
}

// gather-mean: one wave per node (lane = feature)
__global__ __launch_bounds__(256) void k_agg(
    const float* __restrict__ h_in,
    const int* __restrict__ row_ptr, const int* __restrict__ col,
    const float* __restrict__ inv_deg,
    float* __restrict__ agg)
{
    int tid = threadIdx.x;
    int wv = tid >> 6, f = tid & 63;
    int g = f >> 4, qoff = (f & 15) * 4;
    for (int node = blockIdx.x*4 + wv; node < NN; node += gridDim.x*4){
        int s0 = row_ptr[node], s1 = row_ptr[node+1];
        float a0 = 0.f, a1 = 0.f, a2 = 0.f, a3 = 0.f;
        for (int p0 = s0; p0 < s1; p0 += 64){
            int cnt = s1 - p0; if (cnt > 64) cnt = 64;
            int cidx = (f < cnt) ? col[p0 + f] : NN;   // NN -> zero row
            int nq = (cnt + 3) >> 2;
            for (int t = 0; t < nq; t++){
                int sidx = __shfl(cidx, t*4 + g);
                float4 v = *(const float4*)&h_in[(size_t)sidx*HIDC + qoff];
                a0 += v.x; a1 += v.y; a2 += v.z; a3 += v.w;
            }
        }
        a0 += __shfl_xor(a0, 16); a0 += __shfl_xor(a0, 32);
        a1 += __shfl_xor(a1, 16); a1 += __shfl_xor(a1, 32);
        a2 += __shfl_xor(a2, 16); a2 += __shfl_xor(a2, 32);
        a3 += __shfl_xor(a3, 16); a3 += __shfl_xor(a3, 32);
        if (g == 0){
            float idg = inv_deg[node];
            float4 o = make_float4(a0*idg, a1*idg, a2*idg, a3*idg);
            *(float4*)&agg[(size_t)node*HIDC + qoff] = o;
        }
    }
}

// ---- register-tiled LDS GEMM kernels (validated round 11) ----

__global__ __launch_bounds__(256) void k_enc(
    const float* __restrict__ x,
    const float* __restrict__ w1, const float* __restrict__ b1,
    const float* __restrict__ w2, const float* __restrict__ b2,
    float* __restrict__ h)
{
    __shared__ float w1s[INC*HIDC];
    __shared__ float w2s[HIDC*HIDC];
    __shared__ float Xt[64*XS];
    __shared__ float T[64*AS];
    int tid = threadIdx.x, tile = blockIdx.x;
    for (int i = tid*4; i < INC*HIDC;  i += 1024)
        *(float4*)&w1s[i] = *(const float4*)&w1[i];
    for (int i = tid*4; i < HIDC*HIDC; i += 1024)
        *(float4*)&w2s[i] = *(const float4*)&w2[i];
    for (int i = tid*4; i < 64*INC; i += 1024){
        int m = i >> 5, k = i & 31;
        int row = tile*64 + m; if (row >= NN) row = NN-1;
        *(float4*)&Xt[m*XS + k] = *(const float4*)&x[(size_t)row*INC + k];
    }
    __syncthreads();
    int tx = tid & 15, ty = tid >> 4;
    int m0 = ty*4, n0 = tx*4;
    float4 b1v = *(const float4*)&b1[n0];
    float acc[4][4];
    #pragma unroll
    for (int r = 0; r < 4; r++){
        acc[r][0]=b1v.x; acc[r][1]=b1v.y; acc[r][2]=b1v.z; acc[r][3]=b1v.w;
    }
    mm_tile<XS, INC>(Xt, w1s, m0, n0, acc);
    #pragma unroll
    for (int r = 0; r < 4; r++){
        float4 o = make_float4(gelu_exact(acc[r][0]), gelu_exact(acc[r][1]),
                               gelu_exact(acc[r][2]), gelu_exact(acc[r][3]));
        *(float4*)&T[(m0+r)*AS + n0] = o;
    }
    __syncthreads();
    float4 b2v = *(const float4*)&b2[n0];
    #pragma unroll
    for (int r = 0; r < 4; r++){
        acc[r][0]=b2v.x; acc[r][1]=b2v.y; acc[r][2]=b2v.z; acc[r][3]=b2v.w;
    }
    mm_tile<AS, HIDC>(T, w2s, m0, n0, acc);
    #pragma unroll
    for (int r = 0; r < 4; r++){
        int node = tile*64 + m0 + r;
        if (node < NN)
            *(float4*)&h[(size_t)node*HIDC + n0] =
                make_float4(acc[r][0], acc[r][1], acc[r][2], acc[r][3]);
    }
}

__global__ __launch_bounds__(256) void k_sage(
    const float* __restrict__ h_in, const float* __restrict__ agg,
    const float* __restrict__ wl, const float* __restrict__ wr,
    const float* __restrict__ bias, float* __restrict__ h_out)
{
    __shared__ float Wl[HIDC*HIDC];
    __shared__ float Wr[HIDC*HIDC];
    __shared__ float At[64*AS];
    int tid = threadIdx.x, tile = blockIdx.x;
    for (int i = tid*4; i < HIDC*HIDC; i += 1024){
        *(float4*)&Wl[i] = *(const float4*)&wl[i];
        *(float4*)&Wr[i] = *(const float4*)&wr[i];
    }
    const float* abase = agg + (size_t)tile*64*HIDC;
    for (int i = tid*4; i < 64*HIDC; i += 1024){
        int m = i >> 6, k = i & 63;
        *(float4*)&At[m*AS + k] = *(const float4*)&abase[i];
    }
    __syncthreads();
    int tx = tid & 15, ty = tid >> 4;
    int m0 = ty*4, n0 = tx*4;
    float4 bv = *(const float4*)&bias[n0];
    float acc[4][4];
    #pragma unroll
    for (int r = 0; r < 4; r++){
        acc[r][0]=bv.x; acc[r][1]=bv.y; acc[r][2]=bv.z; acc[r][3]=bv.w;
    }
    mm_tile<AS, HIDC>(At, Wl, m0, n0, acc);
    __syncthreads();
    const float* hbase = h_in + (size_t)tile*64*HIDC;
    for (int i = tid*4; i < 64*HIDC; i += 1024){
        int m = i >> 6, k = i & 63;
        *(float4*)&At[m*AS + k] = *(const float4*)&hbase[i];
    }
    __syncthreads();
    mm_tile<AS, HIDC>(At, Wr, m0, n0, acc);
    #pragma unroll
    for (int r = 0; r < 4; r++){
        int node = tile*64 + m0 + r;
        if (node < NN)
            *(float4*)&h_out[(size_t)node*HIDC + n0] =
                make_float4(gelu_exact(acc[r][0]), gelu_exact(acc[r][1]),
                            gelu_exact(acc[r][2]), gelu_exact(acc[r][3]));
    }
}

__global__ __launch_bounds__(256) void k_dec(
    const float* __restrict__ hbuf,
    const float* __restrict__ w1, const float* __restrict__ b1,
    const float* __restrict__ w2, const float* __restrict__ b2,
    float* __restrict__ out)
{
    __shared__ float w1s[HIDC*HIDC];
    __shared__ float w2s[HIDC*OUTC];
    __shared__ float At[64*AS];
    __shared__ float T[64*AS];
    int tid = threadIdx.x, tile = blockIdx.x;
    for (int i = tid*4; i < HIDC*HIDC; i += 1024)
        *(float4*)&w1s[i] = *(const float4*)&w1[i];
    if (tid*4 < HIDC*OUTC)
        *(float4*)&w2s[tid*4] = *(const float4*)&w2[tid*4];
    const float* hbase = hbuf + (size_t)tile*64*HIDC;
    for (int i = tid*4; i < 64*HIDC; i += 1024){
        int m = i >> 6, k = i & 63;
        *(float4*)&At[m*AS + k] = *(const float4*)&hbase[i];
    }
    __syncthreads();
    int tx = tid & 15, ty = tid >> 4;
    int m0 = ty*4, n0 = tx*4;
    float4 b1v = *(const float4*)&b1[n0];
    float acc[4][4];
    #pragma unroll
    for (int r = 0; r < 4; r++){
        acc[r][0]=b1v.x; acc[r][1]=b1v.y; acc[r][2]=b1v.z; acc[r][3]=b1v.w;
    }
    mm_tile<AS, HIDC>(At, w1s, m0, n0, acc);
    #pragma unroll
    for (int r = 0; r < 4; r++){
        float4 o = make_float4(gelu_exact(acc[r][0]), gelu_exact(acc[r][1]),
                               gelu_exact(acc[r][2]), gelu_exact(acc[r][3]));
        *(float4*)&T[(m0+r)*AS + n0] = o;
    }
    __syncthreads();
    int m = tid >> 2, c0 = (tid & 3) * 2;
    float a0 = b2[c0], a1 = b2[c0+1];
    #pragma unroll 4
    for (int k = 0; k < HIDC; k++){
        float tv = T[m*AS + k];
        float2 wv = *(const float2*)&w2s[k*OUTC + c0];
        a0 = fmaf(tv, wv.x, a0);
        a1 = fmaf(tv, wv.y, a1);
    }
    int node = tile*64 + m;
    if (node < NN)
        *(float2*)&out[(size_t)node*OUTC + c0] = make_float2(a0, a1);
}

extern "C" void kernel_launch(void* const* d_in, const int* in_sizes, int n_in,
                              void* d_out, int out_size, void* d_ws, size_t ws_size,
                              hipStream_t stream){
    const float* x      = (const float*)d_in[0];
    const int*   ei     = (const int*)  d_in[1];
    const float* enc_w1 = (const float*)d_in[2];
    const float* enc_b1 = (const float*)d_in[3];
    const float* enc_w2 = (const float*)d_in[4];
    const float* enc_b2 = (const float*)d_in[5];
    const float* sage_wl= (const float*)d_in[6];
    const float* sage_wr= (const float*)d_in[7];
    const float* sage_b = (const float*)d_in[8];
    const float* dec_w1 = (const float*)d_in[9];
    const float* dec_b1 = (const float*)d_in[10];
    const float* dec_w2 = (const float*)d_in[11];
    const float* dec_b2 = (const float*)d_in[12];
    float* out = (float*)d_out;

    char* ws = (char*)d_ws;
    size_t off = 0;
    auto alloc = [&](size_t bytes)->void*{
        void* p = ws + off; off = (off + bytes + 255) & ~(size_t)255; return p;
    };
    int*   cnts     = (int*)  alloc((size_t)NCH*NBK2*4);
    int*   lboff    = (int*)  alloc((size_t)NCH*NBK2*4);
    int*   choff    = (int*)  alloc((size_t)NBK2*NCH*4);
    int*   btot     = (int*)  alloc((size_t)NBK2*4);
    int*   bbase    = (int*)  alloc((size_t)NBK2*4);
    int*   row_ptr  = (int*)  alloc((size_t)(NN+1)*4);
    int*   col      = (int*)  alloc((size_t)NE*4);
    float* inv_deg  = (float*)alloc((size_t)NN*4);
    float* h0       = (float*)alloc((size_t)NPAD*HIDC*4);
    float* h1       = (float*)alloc((size_t)NPAD*HIDC*4);
    float* agg      = (float*)alloc((size_t)NPAD*HIDC*4);
    int2*  ebuf     = (int2*)agg;   // disjoint lifetime: build vs layers

    const int* srcv = ei;        // edge_index row 0
    const int* dstv = ei + NE;   // edge_index row 1

    hipLaunchKernelGGL(k_ebin,  dim3(NCH),  dim3(256), 0, stream,
                       srcv, dstv, ebuf, cnts, lboff);
    hipLaunchKernelGGL(k_choff, dim3(NBK2), dim3(256), 0, stream,
                       cnts, choff, btot);
    hipLaunchKernelGGL(k_bbase, dim3(1),    dim3(256), 0, stream,
                       btot, bbase, h0, h1, row_ptr);
    hipLaunchKernelGGL(k_bsort, dim3(NBK2), dim3(256), 0, stream,
                       ebuf, lboff, choff, btot, bbase, row_ptr, col, inv_deg);

    hipLaunchKernelGGL(k_enc, dim3(NT_TILES), dim3(256), 0, stream,
                       x, enc_w1, enc_b1, enc_w2, enc_b2, h0);

    const float* hin = h0; float* hout = h1;
    for (int l = 0; l < 3; l++){
        hipLaunchKernelGGL(k_agg, dim3(2048), dim3(256), 0, stream,
                           hin, row_ptr, col, inv_deg, agg);
        hipLaunchKernelGGL(k_sage, dim3(NT_TILES), dim3(256), 0, stream,
                           hin, agg,
                           sage_wl + (size_t)l*HIDC*HIDC,
                           sage_wr + (size_t)l*HIDC*HIDC,
                           sage_b  + (size_t)l*HIDC,
                           hout);
        float* t = (float*)hin; hin = hout; hout = t;
    }

    hipLaunchKernelGGL(k_dec, dim3(NT_TILES), dim3(256), 0, stream,
                       hin, dec_w1, dec_b1, dec_w2, dec_b2, out);
}

// Round 13
// 225.847 us; speedup vs baseline: 3.6881x; 1.0799x over previous
//
#include <hip/hip_runtime.h>
#include <math.h>

#define NN 50000
#define NE 800000
#define INC 32
#define HIDC 64
#define OUTC 8
#define NT_TILES ((NN + 63) / 64)      // 782
#define NPAD (NT_TILES * 64)           // 50048 padded rows
#define AS 68                           // LDS stride for 64-wide tiles
#define XS 36                           // LDS stride for 32-wide x tile
#define NCH 250                         // edge chunks (level 0 blocks)
#define ECHK (NE / NCH)                 // 3200 edges per chunk
#define BKD 128                         // dsts per fine bucket
#define NBK2 ((NN + BKD - 1) / BKD)     // 391 buckets
#define EC 12                           // register-cached edges per thread

__device__ __forceinline__ float gelu_exact(float x){
    return 0.5f * x * (1.0f + erff(x * 0.70710678118654752f));
}

// register-tiled 4x4 GEMM inner loop: acc[r][c] += At[m0+r][k] * Ws[k][n0+c]
template<int ST, int KK>
__device__ __forceinline__ void mm_tile(const float* __restrict__ At,
                                        const float* __restrict__ Ws,
                                        int m0, int n0, float acc[4][4])
{
    #pragma unroll 2
    for (int k = 0; k < KK; k += 2){
        float2 av[4];
        #pragma unroll
        for (int r = 0; r < 4; r++)
            av[r] = *(const float2*)&At[(m0+r)*ST + k];
        float4 w0 = *(const float4*)&Ws[(k+0)*HIDC + n0];
        float4 w1 = *(const float4*)&Ws[(k+1)*HIDC + n0];
        #pragma unroll
        for (int r = 0; r < 4; r++){
            acc[r][0] = fmaf(av[r].x, w0.x, acc[r][0]);
            acc[r][1] = fmaf(av[r].x, w0.y, acc[r][1]);
            acc[r][2] = fmaf(av[r].x, w0.z, acc[r][2]);
            acc[r][3] = fmaf(av[r].x, w0.w, acc[r][3]);
            acc[r][0] = fmaf(av[r].y, w1.x, acc[r][0]);
            acc[r][1] = fmaf(av[r].y, w1.y, acc[r][1]);
            acc[r][2] = fmaf(av[r].y, w1.z, acc[r][2]);
            acc[r][3] = fmaf(av[r].y, w1.w, acc[r][3]);
        }
    }
}

// ---- CSR build v2: two-level bucket sort, single-writer regions,
// 391 fine buckets (128 dsts), register-cached edges in k_bsort ----

// level 0: bin each 3200-edge chunk by bucket (dst>>7) into the chunk's
// private ebuf region; record per-(chunk,bucket) counts+offsets.
__global__ __launch_bounds__(512) void k_ebin(
    const int* __restrict__ src, const int* __restrict__ dst,
    int2* __restrict__ ebuf, int* __restrict__ cnts, int* __restrict__ lboff)
{
    __shared__ int cnt[512];
    __shared__ int cur[512];
    int c = blockIdx.x, tid = threadIdx.x;
    cnt[tid] = 0;
    __syncthreads();
    int e0 = c*ECHK;
    for (int i = e0 + tid; i < e0 + ECHK; i += 512)
        atomicAdd(&cnt[dst[i] >> 7], 1);
    __syncthreads();
    int v = cnt[tid];
    for (int off = 1; off < 512; off <<= 1){
        int t = (tid >= off) ? cnt[tid-off] : 0;
        __syncthreads();
        cnt[tid] += t;
        __syncthreads();
    }
    int excl = cnt[tid] - v;
    if (tid < NBK2){
        cnts[c*NBK2 + tid]  = v;
        lboff[c*NBK2 + tid] = excl;
    }
    cur[tid] = excl;
    __syncthreads();
    for (int i = e0 + tid; i < e0 + ECHK; i += 512){
        int d = dst[i], s = src[i];
        int p = atomicAdd(&cur[d >> 7], 1);
        ebuf[e0 + p] = make_int2(d, s);
    }
}

// level 0.5: per-bucket exclusive prefix over the 250 chunk counts
__global__ __launch_bounds__(256) void k_choff(
    const int* __restrict__ cnts, int* __restrict__ choff, int* __restrict__ btot)
{
    __shared__ int sd[256];
    int b = blockIdx.x, tid = threadIdx.x;
    int v = (tid < NCH) ? cnts[tid*NBK2 + b] : 0;
    sd[tid] = v;
    __syncthreads();
    for (int off = 1; off < 256; off <<= 1){
        int t = (tid >= off) ? sd[tid-off] : 0;
        __syncthreads();
        sd[tid] += t;
        __syncthreads();
    }
    if (tid < NCH) choff[b*NCH + tid] = sd[tid] - v;
    if (tid == 255) btot[b] = sd[255];
}

// bucket bases (scan over 391 totals) + misc init
__global__ __launch_bounds__(512) void k_bbase(
    const int* __restrict__ btot, int* __restrict__ bbase,
    float* h0, float* h1, int* row_ptr)
{
    __shared__ int sd[512];
    int tid = threadIdx.x;
    int v = (tid < NBK2) ? btot[tid] : 0;
    sd[tid] = v;
    __syncthreads();
    for (int off = 1; off < 512; off <<= 1){
        int t = (tid >= off) ? sd[tid-off] : 0;
        __syncthreads();
        sd[tid] += t;
        __syncthreads();
    }
    if (tid < NBK2) bbase[tid] = sd[tid] - v;
    if (tid == 0) row_ptr[NN] = NE;
    if (tid < 64){
        h0[(size_t)NN*HIDC + tid] = 0.f;
        h1[(size_t)NN*HIDC + tid] = 0.f;
    }
}

// level 1: block b owns bucket b (128 dsts). One binary search per edge;
// (dst,src) cached in statically-indexed registers between the histogram
// pass and the scatter pass (overflow loop keeps worst-case correctness).
__global__ __launch_bounds__(256) void k_bsort(
    const int2* __restrict__ ebuf, const int* __restrict__ lboff,
    const int* __restrict__ choff, const int* __restrict__ btot,
    const int* __restrict__ bbase,
    int* __restrict__ row_ptr, int* __restrict__ col,
    float* __restrict__ inv_deg)
{
    __shared__ int cum[NCH];
    __shared__ int lb[NCH];
    __shared__ int hcnt[BKD];
    __shared__ int fpos[BKD];
    int b = blockIdx.x, tid = threadIdx.x;
    if (tid < NCH){
        cum[tid] = choff[b*NCH + tid];
        lb[tid]  = lboff[tid*NBK2 + b];
    }
    if (tid < BKD) hcnt[tid] = 0;
    __syncthreads();
    int tot = btot[b];
    int lo = b << 7;
    int dl[EC], sv[EC];
    #pragma unroll
    for (int j = 0; j < EC; j++){
        int e = tid + j*256;
        dl[j] = -1; sv[j] = 0;
        if (e < tot){
            int lc = 0, hc = NCH;
            while (hc - lc > 1){ int mid = (lc+hc) >> 1; if (cum[mid] <= e) lc = mid; else hc = mid; }
            int2 pr = ebuf[lc*ECHK + lb[lc] + (e - cum[lc])];
            dl[j] = pr.x - lo; sv[j] = pr.y;
            atomicAdd(&hcnt[dl[j]], 1);
        }
    }
    for (int e = tid + EC*256; e < tot; e += 256){       // rare overflow
        int lc = 0, hc = NCH;
        while (hc - lc > 1){ int mid = (lc+hc) >> 1; if (cum[mid] <= e) lc = mid; else hc = mid; }
        int2 pr = ebuf[lc*ECHK + lb[lc] + (e - cum[lc])];
        atomicAdd(&hcnt[pr.x - lo], 1);
    }
    __syncthreads();
    int v = (tid < BKD) ? hcnt[tid] : 0;
    for (int off = 1; off < BKD; off <<= 1){
        int t = (tid >= off && tid < BKD) ? hcnt[tid-off] : 0;
        __syncthreads();
        if (tid < BKD) hcnt[tid] += t;
        __syncthreads();
    }
    int base = bbase[b];
    if (tid < BKD){
        int excl = hcnt[tid] - v;
        int g = lo + tid;
        if (g < NN){
            row_ptr[g] = base + excl;
            inv_deg[g] = 1.0f / (float)max(v, 1);
        }
        fpos[tid] = base + excl;
    }
    __syncthreads();
    #pragma unroll
    for (int j = 0; j < EC; j++){
        if (dl[j] >= 0){
            int q = atomicAdd(&fpos[dl[j]], 1);
            col[q] = sv[j];
        }
    }
    for (int e = tid + EC*256; e < tot; e += 256){       // rare overflow
        int lc = 0, hc = NCH;
        while (hc - lc > 1){ int mid = (lc+hc) >> 1; if (cum[mid] <= e) lc = mid; else hc = mid; }
        int2 pr = ebuf[lc*ECHK + lb[lc] + (e - cum[lc])];
        int q = atomicAdd(&fpos[pr.x - lo], 1);
        col[q] = pr.y;
    }
}

// gather-mean: one wave per node (lane = feature)
__global__ __launch_bounds__(256) void k_agg(
    const float* __restrict__ h_in,
    const int* __restrict__ row_ptr, const int* __restrict__ col,
    const float* __restrict__ inv_deg,
    float* __restrict__ agg)
{
    int tid = threadIdx.x;
    int wv = tid >> 6, f = tid & 63;
    int g = f >> 4, qoff = (f & 15) * 4;
    for (int node = blockIdx.x*4 + wv; node < NN; node += gridDim.x*4){
        int s0 = row_ptr[node], s1 = row_ptr[node+1];
        float a0 = 0.f, a1 = 0.f, a2 = 0.f, a3 = 0.f;
        for (int p0 = s0; p0 < s1; p0 += 64){
            int cnt = s1 - p0; if (cnt > 64) cnt = 64;
            int cidx = (f < cnt) ? col[p0 + f] : NN;   // NN -> zero row
            int nq = (cnt + 3) >> 2;
            for (int t = 0; t < nq; t++){
                int sidx = __shfl(cidx, t*4 + g);
                float4 v = *(const float4*)&h_in[(size_t)sidx*HIDC + qoff];
                a0 += v.x; a1 += v.y; a2 += v.z; a3 += v.w;
            }
        }
        a0 += __shfl_xor(a0, 16); a0 += __shfl_xor(a0, 32);
        a1 += __shfl_xor(a1, 16); a1 += __shfl_xor(a1, 32);
        a2 += __shfl_xor(a2, 16); a2 += __shfl_xor(a2, 32);
        a3 += __shfl_xor(a3, 16); a3 += __shfl_xor(a3, 32);
        if (g == 0){
            float idg = inv_deg[node];
            float4 o = make_float4(a0*idg, a1*idg, a2*idg, a3*idg);
            *(float4*)&agg[(size_t)node*HIDC + qoff] = o;
        }
    }
}

// ---- register-tiled LDS GEMM kernels (validated round 11) ----

__global__ __launch_bounds__(256) void k_enc(
    const float* __restrict__ x,
    const float* __restrict__ w1, const float* __restrict__ b1,
    const float* __restrict__ w2, const float* __restrict__ b2,
    float* __restrict__ h)
{
    __shared__ float w1s[INC*HIDC];
    __shared__ float w2s[HIDC*HIDC];
    __shared__ float Xt[64*XS];
    __shared__ float T[64*AS];
    int tid = threadIdx.x, tile = blockIdx.x;
    for (int i = tid*4; i < INC*HIDC;  i += 1024)
        *(float4*)&w1s[i] = *(const float4*)&w1[i];
    for (int i = tid*4; i < HIDC*HIDC; i += 1024)
        *(float4*)&w2s[i] = *(const float4*)&w2[i];
    for (int i = tid*4; i < 64*INC; i += 1024){
        int m = i >> 5, k = i & 31;
        int row = tile*64 + m; if (row >= NN) row = NN-1;
        *(float4*)&Xt[m*XS + k] = *(const float4*)&x[(size_t)row*INC + k];
    }
    __syncthreads();
    int tx = tid & 15, ty = tid >> 4;
    int m0 = ty*4, n0 = tx*4;
    float4 b1v = *(const float4*)&b1[n0];
    float acc[4][4];
    #pragma unroll
    for (int r = 0; r < 4; r++){
        acc[r][0]=b1v.x; acc[r][1]=b1v.y; acc[r][2]=b1v.z; acc[r][3]=b1v.w;
    }
    mm_tile<XS, INC>(Xt, w1s, m0, n0, acc);
    #pragma unroll
    for (int r = 0; r < 4; r++){
        float4 o = make_float4(gelu_exact(acc[r][0]), gelu_exact(acc[r][1]),
                               gelu_exact(acc[r][2]), gelu_exact(acc[r][3]));
        *(float4*)&T[(m0+r)*AS + n0] = o;
    }
    __syncthreads();
    float4 b2v = *(const float4*)&b2[n0];
    #pragma unroll
    for (int r = 0; r < 4; r++){
        acc[r][0]=b2v.x; acc[r][1]=b2v.y; acc[r][2]=b2v.z; acc[r][3]=b2v.w;
    }
    mm_tile<AS, HIDC>(T, w2s, m0, n0, acc);
    #pragma unroll
    for (int r = 0; r < 4; r++){
        int node = tile*64 + m0 + r;
        if (node < NN)
            *(float4*)&h[(size_t)node*HIDC + n0] =
                make_float4(acc[r][0], acc[r][1], acc[r][2], acc[r][3]);
    }
}

__global__ __launch_bounds__(256) void k_sage(
    const float* __restrict__ h_in, const float* __restrict__ agg,
    const float* __restrict__ wl, const float* __restrict__ wr,
    const float* __restrict__ bias, float* __restrict__ h_out)
{
    __shared__ float Wl[HIDC*HIDC];
    __shared__ float Wr[HIDC*HIDC];
    __shared__ float At[64*AS];
    int tid = threadIdx.x, tile = blockIdx.x;
    for (int i = tid*4; i < HIDC*HIDC; i += 1024){
        *(float4*)&Wl[i] = *(const float4*)&wl[i];
        *(float4*)&Wr[i] = *(const float4*)&wr[i];
    }
    const float* abase = agg + (size_t)tile*64*HIDC;
    for (int i = tid*4; i < 64*HIDC; i += 1024){
        int m = i >> 6, k = i & 63;
        *(float4*)&At[m*AS + k] = *(const float4*)&abase[i];
    }
    __syncthreads();
    int tx = tid & 15, ty = tid >> 4;
    int m0 = ty*4, n0 = tx*4;
    float4 bv = *(const float4*)&bias[n0];
    float acc[4][4];
    #pragma unroll
    for (int r = 0; r < 4; r++){
        acc[r][0]=bv.x; acc[r][1]=bv.y; acc[r][2]=bv.z; acc[r][3]=bv.w;
    }
    mm_tile<AS, HIDC>(At, Wl, m0, n0, acc);
    __syncthreads();
    const float* hbase = h_in + (size_t)tile*64*HIDC;
    for (int i = tid*4; i < 64*HIDC; i += 1024){
        int m = i >> 6, k = i & 63;
        *(float4*)&At[m*AS + k] = *(const float4*)&hbase[i];
    }
    __syncthreads();
    mm_tile<AS, HIDC>(At, Wr, m0, n0, acc);
    #pragma unroll
    for (int r = 0; r < 4; r++){
        int node = tile*64 + m0 + r;
        if (node < NN)
            *(float4*)&h_out[(size_t)node*HIDC + n0] =
                make_float4(gelu_exact(acc[r][0]), gelu_exact(acc[r][1]),
                            gelu_exact(acc[r][2]), gelu_exact(acc[r][3]));
    }
}

__global__ __launch_bounds__(256) void k_dec(
    const float* __restrict__ hbuf,
    const float* __restrict__ w1, const float* __restrict__ b1,
    const float* __restrict__ w2, const float* __restrict__ b2,
    float* __restrict__ out)
{
    __shared__ float w1s[HIDC*HIDC];
    __shared__ float w2s[HIDC*OUTC];
    __shared__ float At[64*AS];
    __shared__ float T[64*AS];
    int tid = threadIdx.x, tile = blockIdx.x;
    for (int i = tid*4; i < HIDC*HIDC; i += 1024)
        *(float4*)&w1s[i] = *(const float4*)&w1[i];
    if (tid*4 < HIDC*OUTC)
        *(float4*)&w2s[tid*4] = *(const float4*)&w2[tid*4];
    const float* hbase = hbuf + (size_t)tile*64*HIDC;
    for (int i = tid*4; i < 64*HIDC; i += 1024){
        int m = i >> 6, k = i & 63;
        *(float4*)&At[m*AS + k] = *(const float4*)&hbase[i];
    }
    __syncthreads();
    int tx = tid & 15, ty = tid >> 4;
    int m0 = ty*4, n0 = tx*4;
    float4 b1v = *(const float4*)&b1[n0];
    float acc[4][4];
    #pragma unroll
    for (int r = 0; r < 4; r++){
        acc[r][0]=b1v.x; acc[r][1]=b1v.y; acc[r][2]=b1v.z; acc[r][3]=b1v.w;
    }
    mm_tile<AS, HIDC>(At, w1s, m0, n0, acc);
    #pragma unroll
    for (int r = 0; r < 4; r++){
        float4 o = make_float4(gelu_exact(acc[r][0]), gelu_exact(acc[r][1]),
                               gelu_exact(acc[r][2]), gelu_exact(acc[r][3]));
        *(float4*)&T[(m0+r)*AS + n0] = o;
    }
    __syncthreads();
    int m = tid >> 2, c0 = (tid & 3) * 2;
    float a0 = b2[c0], a1 = b2[c0+1];
    #pragma unroll 4
    for (int k = 0; k < HIDC; k++){
        float tv = T[m*AS + k];
        float2 wv = *(const float2*)&w2s[k*OUTC + c0];
        a0 = fmaf(tv, wv.x, a0);
        a1 = fmaf(tv, wv.y, a1);
    }
    int node = tile*64 + m;
    if (node < NN)
        *(float2*)&out[(size_t)node*OUTC + c0] = make_float2(a0, a1);
}

extern "C" void kernel_launch(void* const* d_in, const int* in_sizes, int n_in,
                              void* d_out, int out_size, void* d_ws, size_t ws_size,
                              hipStream_t stream){
    const float* x      = (const float*)d_in[0];
    const int*   ei     = (const int*)  d_in[1];
    const float* enc_w1 = (const float*)d_in[2];
    const float* enc_b1 = (const float*)d_in[3];
    const float* enc_w2 = (const float*)d_in[4];
    const float* enc_b2 = (const float*)d_in[5];
    const float* sage_wl= (const float*)d_in[6];
    const float* sage_wr= (const float*)d_in[7];
    const float* sage_b = (const float*)d_in[8];
    const float* dec_w1 = (const float*)d_in[9];
    const float* dec_b1 = (const float*)d_in[10];
    const float* dec_w2 = (const float*)d_in[11];
    const float* dec_b2 = (const float*)d_in[12];
    float* out = (float*)d_out;

    char* ws = (char*)d_ws;
    size_t off = 0;
    auto alloc = [&](size_t bytes)->void*{
        void* p = ws + off; off = (off + bytes + 255) & ~(size_t)255; return p;
    };
    int*   cnts     = (int*)  alloc((size_t)NCH*NBK2*4);
    int*   lboff    = (int*)  alloc((size_t)NCH*NBK2*4);
    int*   choff    = (int*)  alloc((size_t)NBK2*NCH*4);
    int*   btot     = (int*)  alloc((size_t)NBK2*4);
    int*   bbase    = (int*)  alloc((size_t)NBK2*4);
    int*   row_ptr  = (int*)  alloc((size_t)(NN+1)*4);
    int*   col      = (int*)  alloc((size_t)NE*4);
    float* inv_deg  = (float*)alloc((size_t)NN*4);
    float* h0       = (float*)alloc((size_t)NPAD*HIDC*4);
    float* h1       = (float*)alloc((size_t)NPAD*HIDC*4);
    float* agg      = (float*)alloc((size_t)NPAD*HIDC*4);
    int2*  ebuf     = (int2*)agg;   // disjoint lifetime: build vs layers

    const int* srcv = ei;        // edge_index row 0
    const int* dstv = ei + NE;   // edge_index row 1

    hipLaunchKernelGGL(k_ebin,  dim3(NCH),  dim3(512), 0, stream,
                       srcv, dstv, ebuf, cnts, lboff);
    hipLaunchKernelGGL(k_choff, dim3(NBK2), dim3(256), 0, stream,
                       cnts, choff, btot);
    hipLaunchKernelGGL(k_bbase, dim3(1),    dim3(512), 0, stream,
                       btot, bbase, h0, h1, row_ptr);
    hipLaunchKernelGGL(k_bsort, dim3(NBK2), dim3(256), 0, stream,
                       ebuf, lboff, choff, btot, bbase, row_ptr, col, inv_deg);

    hipLaunchKernelGGL(k_enc, dim3(NT_TILES), dim3(256), 0, stream,
                       x, enc_w1, enc_b1, enc_w2, enc_b2, h0);

    const float* hin = h0; float* hout = h1;
    for (int l = 0; l < 3; l++){
        hipLaunchKernelGGL(k_agg, dim3(2048), dim3(256), 0, stream,
                           hin, row_ptr, col, inv_deg, agg);
        hipLaunchKernelGGL(k_sage, dim3(NT_TILES), dim3(256), 0, stream,
                           hin, agg,
                           sage_wl + (size_t)l*HIDC*HIDC,
                           sage_wr + (size_t)l*HIDC*HIDC,
                           sage_b  + (size_t)l*HIDC,
                           hout);
        float* t = (float*)hin; hin = hout; hout = t;
    }

    hipLaunchKernelGGL(k_dec, dim3(NT_TILES), dim3(256), 0, stream,
                       hin, dec_w1, dec_b1, dec_w2, dec_b2, out);
}